// Round 3
// baseline (213.823 us; speedup 1.0000x reference)
//
#include <hip/hip_runtime.h>
#include <cstddef>

#define B_   16
#define C_   256
#define HW_  4096

typedef __attribute__((ext_vector_type(8)))  short bf16x8;
typedef __attribute__((ext_vector_type(16))) float f32x16;

static __device__ __forceinline__ unsigned short f2bf(float f) {
    unsigned int u = __float_as_uint(f);
    u += 0x7fffu + ((u >> 16) & 1u);          // RNE
    return (unsigned short)(u >> 16);
}

// ---------------------------------------------------------------------------
// Kernel E: fused square + NCHW->NHWC bf16 + per-(b,q,h) energy argmax
// partials. grid = (b,h) = 1024 blocks x 256 thr. Stores go through an LDS
// transpose so global writes are 512B-contiguous per 32-lane group.
// ---------------------------------------------------------------------------
__global__ __launch_bounds__(256) void fused_energy(const float* __restrict__ x,
                                                    unsigned short* __restrict__ xsqN,
                                                    float* __restrict__ pval,
                                                    int* __restrict__ pidx) {
    int blk = blockIdx.x;
    int b = blk >> 6, h = blk & 63;
    int tid = threadIdx.x;
    int w = tid & 63, layer = tid >> 6;
    __shared__ float earr[4][4][64];
    __shared__ unsigned short tile[64][264];   // row stride 264 ush = 528B (16B-mult, bank-spread)
    float e0 = 0.f, e1 = 0.f, e2 = 0.f, e3 = 0.f;
    const float* xb = x + (size_t)b * C_ * HW_ + h * 64 + w;
#pragma unroll
    for (int i = 0; i < 8; ++i) {
        int c0 = (i * 4 + layer) * 8;
        union { unsigned short us[8]; int4 v; } u;
        float es = 0.f;
#pragma unroll
        for (int k = 0; k < 8; ++k) {
            float v = xb[(size_t)(c0 + k) * HW_];
            float s = v * v;
            es += s;
            u.us[k] = f2bf(s);
        }
        *(int4*)&tile[w][c0] = u.v;
        if ((i >> 1) == 0) e0 += es;
        else if ((i >> 1) == 1) e1 += es;
        else if ((i >> 1) == 2) e2 += es;
        else e3 += es;
    }
    earr[layer][0][w] = e0; earr[layer][1][w] = e1;
    earr[layer][2][w] = e2; earr[layer][3][w] = e3;
    __syncthreads();
    // contiguous NHWC stores: 32 lanes cover one 512B row segment
    size_t base = (size_t)(b * 64 + h) * 64 * 256;
#pragma unroll
    for (int it = 0; it < 8; ++it) {
        int row  = it * 8 + (tid >> 5);
        int col8 = (tid & 31) * 8;
        *(int4*)(xsqN + base + (size_t)row * 256 + col8) = *(int4*)&tile[row][col8];
    }
    int q = tid >> 6;
    float ev = earr[0][q][w] + earr[1][q][w] + earr[2][q][w] + earr[3][q][w];
    int ix = h * 64 + w;
#pragma unroll
    for (int off = 32; off; off >>= 1) {
        float ov = __shfl_down(ev, off);
        int   oi = __shfl_down(ix, off);
        if (ov > ev || (ov == ev && oi < ix)) { ev = ov; ix = oi; }
    }
    if ((tid & 63) == 0) {
        pval[(b * 64 + h) * 4 + q] = ev;
        pidx[(b * 64 + h) * 4 + q] = ix;
    }
}

// ---------------------------------------------------------------------------
// Final argmax over h per (b,q). grid = 64 blocks (b*4+q) x 64 thr.
// ---------------------------------------------------------------------------
__global__ __launch_bounds__(64) void energy_final(const float* __restrict__ pval,
                                                   const int* __restrict__ pidx,
                                                   int* __restrict__ lm) {
    int bq = blockIdx.x;
    int b = bq >> 2, q = bq & 3;
    int h = threadIdx.x;
    float ev = pval[(b * 64 + h) * 4 + q];
    int   ix = pidx[(b * 64 + h) * 4 + q];
#pragma unroll
    for (int off = 32; off; off >>= 1) {
        float ov = __shfl_down(ev, off);
        int   oi = __shfl_down(ix, off);
        if (ov > ev || (ov == ev && oi < ix)) { ev = ov; ix = oi; }
    }
    if (h == 0) lm[bq] = ix;
}

// ---------------------------------------------------------------------------
// Landmark value table Lval[b][c] (bf16). 16 blocks x 256 thr.
// ---------------------------------------------------------------------------
__global__ __launch_bounds__(256) void lval_kernel(const unsigned short* __restrict__ xsqN,
                                                   const int* __restrict__ lm,
                                                   unsigned short* __restrict__ Lval) {
    int t = blockIdx.x * 256 + threadIdx.x;   // b*256 + c
    int b = t >> 8, c = t & 255, q = c >> 6;
    int l = lm[b * 4 + q];
    Lval[t] = xsqN[((size_t)((b * 64 + (l >> 6)) * 64 + (l & 63))) * 256 + c];
}

// ---------------------------------------------------------------------------
// Weight pack -> fragment-ordered bf16 (unchanged, verified).
// Chunk (j,cib) = 16KB contiguous: offset (j*8+cib)*8192 ushorts.
// ---------------------------------------------------------------------------
__global__ __launch_bounds__(64) void wt_pack(const float* __restrict__ w,
                                              unsigned short* __restrict__ wa) {
    int blk  = blockIdx.x;
    int lane = threadIdx.x;
    int cog = blk & 7;
    int s   = (blk >> 3) & 1;
    int cib = (blk >> 4) & 7;
    int j   = blk >> 7;
    int co  = cog * 32 + (lane & 31);
    int k0  = cib * 32 + s * 16 + (lane >> 5) * 8;
    union { unsigned short us[8]; int4 v; } u;
#pragma unroll
    for (int jj = 0; jj < 8; ++jj) {
        int ci = k0 + jj;
        u.us[jj] = f2bf(w[(size_t)(co * 256 + ci) * 9 + j]);
    }
    *(int4*)(wa + ((size_t)blk * 64 + lane) * 8) = u.v;
}

// ---------------------------------------------------------------------------
// Conv: implicit-GEMM bf16 MFMA.
//   A (weights): direct global->VGPR in fragment order, SOFTWARE-PIPELINED at
//     half-tap granularity: while half h's 8 MFMAs issue (~520 cy of shared
//     matrix pipe), half h+1's 4 A-loads are in flight (counted vmcnt keeps
//     them outstanding). This takes the L2/L3 A-load latency off the per-tap
//     critical path that pinned MfmaUtil at 35%.
//   B (image tile): LDS, double-buffered per cib; ONE barrier per cib.
//     B global prefetch issues at half h==1 so its FIFO shadow on subsequent
//     A-waits is <= ~1 half instead of a full HBM stall at tap 0.
//   No setprio: lockstep 2-wave/SIMD structure (m190: setprio hurts there).
// Block: 512 thr = 8 waves; tile 256co x 256px (4 rows). Wave: 128co x 64px.
// Grid 256 = 1 block/CU.
// ---------------------------------------------------------------------------
__global__ __launch_bounds__(512, 2) void conv_mfma(const unsigned short* __restrict__ xsqN,
                                                    const unsigned short* __restrict__ wa,
                                                    const float* __restrict__ bias,
                                                    const int* __restrict__ lm,
                                                    const unsigned short* __restrict__ Lval,
                                                    float* __restrict__ out) {
    int pt = blockIdx.x;              // b*16 + hq
    int b  = pt >> 4;
    int h0 = (pt & 15) * 4;
    int tid  = threadIdx.x;
    int lane = tid & 63;
    int wv   = tid >> 6;
    int wy = wv >> 2, wx = wv & 3;    // co half / image row
    int l31 = lane & 31, qh = lane >> 5;

    __shared__ unsigned short Bs[2][6 * 66 * 40];   // 63.4 KB

    f32x16 acc[4][2];
#pragma unroll
    for (int mt = 0; mt < 4; ++mt)
#pragma unroll
        for (int nt = 0; nt < 2; ++nt)
#pragma unroll
            for (int r = 0; r < 16; ++r) acc[mt][nt][r] = 0.f;

    int4 sv[4];   // B prefetch registers (live across one cib)

    // ---- prologue: stage B(cib=0) with rect-max into Bs[0]
    {
#pragma unroll
        for (int t2 = 0; t2 < 4; ++t2) {
            int idx = tid + t2 * 512;
            int4 v = {0, 0, 0, 0};
            if (idx < 1584) {
                int pr = idx / 264; int rem = idx - pr * 264;
                int pc = rem >> 2;  int part = rem & 3;
                int grow = h0 - 1 + pr, gcol = pc - 1;
                if ((unsigned)grow < 64u && (unsigned)gcol < 64u)
                    v = *(const int4*)(xsqN + (((size_t)(b * 64 + grow) * 64 + gcol) * 256 + part * 8));
            }
            sv[t2] = v;
        }
        int l = lm[b * 4 + 0];
        int hm = l >> 6, wm = l & 63;
#pragma unroll
        for (int t2 = 0; t2 < 4; ++t2) {
            int idx = tid + t2 * 512;
            if (idx < 1584) {
                int pr = idx / 264; int rem = idx - pr * 264;
                int pc = rem >> 2;  int part = rem & 3;
                int grow = h0 - 1 + pr, gcol = pc - 1;
                union { int4 v; unsigned short us[8]; } u; u.v = sv[t2];
                bool inb = ((unsigned)grow < 64u) && ((unsigned)gcol < 64u);
                if (inb && grow <= hm && gcol <= wm) {     // quadrant 0: h<=hm, w<=wm
                    union { int4 v; unsigned short us[8]; } Lu;
                    Lu.v = *(const int4*)(Lval + b * 256 + part * 8);
#pragma unroll
                    for (int k = 0; k < 8; ++k)
                        if (Lu.us[k] > u.us[k]) u.us[k] = Lu.us[k];
                }
                *(int4*)(&Bs[0][(pr * 66 + pc) * 40 + part * 8]) = u.v;
            }
        }
    }
    __syncthreads();

    // A fragment base for this wave (16B frag units):
    //   frag[(j*8+cib)*1024 + (s*8 + wy*4 + m)*64 + lane]
    const bf16x8* Abase = (const bf16x8*)wa + (wy << 8) + lane;   // wy*4*64 + lane

    bf16x8 areg[2][4];
    // preload half (cib=0, j=0, s=0) into buffer 0
    {
        const bf16x8* Ap = Abase;
        areg[0][0] = Ap[0];
        areg[0][1] = Ap[64];
        areg[0][2] = Ap[128];
        areg[0][3] = Ap[192];
    }

    for (int cib = 0; cib < 8; ++cib) {
        const unsigned short* Bb = &Bs[cib & 1][0];
        const bf16x8* Ac = Abase + ((size_t)cib << 10);

#pragma unroll
        for (int j = 0; j < 9; ++j) {
            int j3 = j / 3;
            int r  = wx + j3;                 // dh+1 = j3
            int w0 = l31 + (j - j3 * 3);      // dw+1 = j%3
            const unsigned short* Bp = Bb + (r * 66 + w0) * 40 + qh * 8;
#pragma unroll
            for (int s = 0; s < 2; ++s) {
                const int h = j * 2 + s;      // half index 0..17 (compile-time)
                const int pb = h & 1;         // current A buffer parity

                // ---- prefetch next half's 4 A fragments into the other buffer
                if (h < 17) {
                    const int hn = h + 1;
                    const int jn = hn >> 1, sn = hn & 1;
                    const bf16x8* Ap = Ac + (size_t)jn * 8192 + (sn << 9);
                    areg[pb ^ 1][0] = Ap[0];
                    areg[pb ^ 1][1] = Ap[64];
                    areg[pb ^ 1][2] = Ap[128];
                    areg[pb ^ 1][3] = Ap[192];
                } else if (cib < 7) {
                    // last half of cib: preload (cib+1, j=0, s=0)
                    const bf16x8* Ap = Abase + ((size_t)(cib + 1) << 10);
                    areg[pb ^ 1][0] = Ap[0];
                    areg[pb ^ 1][1] = Ap[64];
                    areg[pb ^ 1][2] = Ap[128];
                    areg[pb ^ 1][3] = Ap[192];
                }

                // ---- B global prefetch for cib+1: issued early in the cib
                // (after first A prefetch so A-waits stay counted, and done
                // long before the store phase consumes sv)
                if (h == 1 && cib < 7) {
                    int nc = cib + 1;
#pragma unroll
                    for (int t2 = 0; t2 < 4; ++t2) {
                        int idx = tid + t2 * 512;
                        int4 v = {0, 0, 0, 0};
                        if (idx < 1584) {
                            int pr = idx / 264; int rem = idx - pr * 264;
                            int pc = rem >> 2;  int part = rem & 3;
                            int grow = h0 - 1 + pr, gcol = pc - 1;
                            if ((unsigned)grow < 64u && (unsigned)gcol < 64u)
                                v = *(const int4*)(xsqN + (((size_t)(b * 64 + grow) * 64 + gcol) * 256 + nc * 32 + part * 8));
                        }
                        sv[t2] = v;
                    }
                }

                // ---- B fragments from LDS for this half
                bf16x8 b0 = *(const bf16x8*)(Bp + s * 16);
                bf16x8 b1 = *(const bf16x8*)(Bp + 1280 + s * 16);

                // ---- 8 MFMAs with the CURRENT half (areg[pb])
                acc[0][0] = __builtin_amdgcn_mfma_f32_32x32x16_bf16(areg[pb][0], b0, acc[0][0], 0, 0, 0);
                acc[0][1] = __builtin_amdgcn_mfma_f32_32x32x16_bf16(areg[pb][0], b1, acc[0][1], 0, 0, 0);
                acc[1][0] = __builtin_amdgcn_mfma_f32_32x32x16_bf16(areg[pb][1], b0, acc[1][0], 0, 0, 0);
                acc[1][1] = __builtin_amdgcn_mfma_f32_32x32x16_bf16(areg[pb][1], b1, acc[1][1], 0, 0, 0);
                acc[2][0] = __builtin_amdgcn_mfma_f32_32x32x16_bf16(areg[pb][2], b0, acc[2][0], 0, 0, 0);
                acc[2][1] = __builtin_amdgcn_mfma_f32_32x32x16_bf16(areg[pb][2], b1, acc[2][1], 0, 0, 0);
                acc[3][0] = __builtin_amdgcn_mfma_f32_32x32x16_bf16(areg[pb][3], b0, acc[3][0], 0, 0, 0);
                acc[3][1] = __builtin_amdgcn_mfma_f32_32x32x16_bf16(areg[pb][3], b1, acc[3][1], 0, 0, 0);
            }
        }

        // ---- B rect-max + store for cib+1 (into other buffer), then the
        //      ONE barrier of this cib.
        if (cib < 7) {
            int nc = cib + 1;
            int l = lm[b * 4 + (nc >> 1)];
            int hm = l >> 6, wm = l & 63;
            bool qhle = (nc >> 1) < 2;
            bool qwle = ((nc >> 1) & 1) == 0;
            unsigned short* Bw = &Bs[(cib + 1) & 1][0];
#pragma unroll
            for (int t2 = 0; t2 < 4; ++t2) {
                int idx = tid + t2 * 512;
                if (idx < 1584) {
                    int pr = idx / 264; int rem = idx - pr * 264;
                    int pc = rem >> 2;  int part = rem & 3;
                    int grow = h0 - 1 + pr, gcol = pc - 1;
                    union { int4 v; unsigned short us[8]; } u; u.v = sv[t2];
                    bool inb = ((unsigned)grow < 64u) && ((unsigned)gcol < 64u);
                    bool hok = qhle ? (grow <= hm) : (grow >= hm);
                    bool wok = qwle ? (gcol <= wm) : (gcol >= wm);
                    if (inb && hok && wok) {
                        union { int4 v; unsigned short us[8]; } Lu;
                        Lu.v = *(const int4*)(Lval + b * 256 + nc * 32 + part * 8);
#pragma unroll
                        for (int k = 0; k < 8; ++k)
                            if (Lu.us[k] > u.us[k]) u.us[k] = Lu.us[k];
                    }
                    *(int4*)(&Bw[(pr * 66 + pc) * 40 + part * 8]) = u.v;
                }
            }
        }
        __syncthreads();
    }

    // ---- epilogue ----
    int h = h0 + wx;
#pragma unroll
    for (int mt = 0; mt < 4; ++mt) {
#pragma unroll
        for (int nt = 0; nt < 2; ++nt) {
#pragma unroll
            for (int r = 0; r < 16; ++r) {
                int row = (r & 3) + 8 * (r >> 2) + 4 * qh;
                int co  = wy * 128 + mt * 32 + row;
                int w   = nt * 32 + l31;
                out[(((size_t)(b * 256 + co)) * 64 + h) * 64 + w] = acc[mt][nt][r] + bias[co];
            }
        }
    }
}

// ---------------------------------------------------------------------------
extern "C" void kernel_launch(void* const* d_in, const int* in_sizes, int n_in,
                              void* d_out, int out_size, void* d_ws, size_t ws_size,
                              hipStream_t stream) {
    const float* x      = (const float*)d_in[0];
    const float* weight = (const float*)d_in[1];
    const float* bias   = (const float*)d_in[2];
    float* out = (float*)d_out;

    char* ws = (char*)d_ws;
    int*            lmp  = (int*)ws;                         // 64 ints @0
    float*          pval = (float*)(ws + 256);               // 4096 f
    int*            pidx = (int*)(ws + 256 + 16384);         // 4096 i
    unsigned short* Lval = (unsigned short*)(ws + 256 + 32768);  // 4096 ush
    unsigned short* Wa   = (unsigned short*)(ws + 49152);    // 1.18 MB
    unsigned short* xsqN = (unsigned short*)(ws + 49152 + 1179648); // NHWC bf16 33.55 MB

    hipLaunchKernelGGL(fused_energy, dim3(1024), dim3(256), 0, stream, x, xsqN, pval, pidx);
    hipLaunchKernelGGL(energy_final, dim3(64), dim3(64), 0, stream, pval, pidx, lmp);
    hipLaunchKernelGGL(lval_kernel, dim3(16), dim3(256), 0, stream, xsqN, lmp, Lval);
    hipLaunchKernelGGL(wt_pack, dim3(1152), dim3(64), 0, stream, weight, Wa);
    hipLaunchKernelGGL(conv_mfma, dim3(256), dim3(512), 0, stream, xsqN, Wa, bias, lmp, Lval, out);
}